// Round 8
// baseline (234.133 us; speedup 1.0000x reference)
//
#include <hip/hip_runtime.h>

#define S_LEN 4096
#define NROWS 16384   // B*S

typedef __attribute__((ext_vector_type(8))) __bf16 bf16x8;
typedef __attribute__((ext_vector_type(8))) unsigned short ushort8;
typedef __attribute__((ext_vector_type(4))) float floatx4;

__device__ __forceinline__ unsigned short f2bf(float f) {   // RNE
    unsigned int u = __float_as_uint(f);
    unsigned int r = (u + 0x7fffu + ((u >> 16) & 1u)) >> 16;
    return (unsigned short)r;
}

__device__ __forceinline__ float fast_exp2(float x) {       // v_exp_f32 (R6-validated)
    return __builtin_amdgcn_exp2f(x);
}

__device__ __forceinline__ unsigned int pack2bf(float a, float b) {
    return (unsigned int)f2bf(a) | ((unsigned int)f2bf(b) << 16);
}

__device__ __forceinline__ bf16x8 cvt_bf16x8(float4 a, float4 b) {
    union { ushort8 u; bf16x8 v; } r;
    r.u[0] = f2bf(a.x); r.u[1] = f2bf(a.y); r.u[2] = f2bf(a.z); r.u[3] = f2bf(a.w);
    r.u[4] = f2bf(b.x); r.u[5] = f2bf(b.y); r.u[6] = f2bf(b.z); r.u[7] = f2bf(b.w);
    return r.v;
}

union frag8 { unsigned int u[4]; bf16x8 v; };

// ---------------- K0: weights fp32 -> bf16 transposed (proven)
__global__ __launch_bounds__(256) void convw_kernel(
    const float* __restrict__ Wq, const float* __restrict__ Wk,
    const float* __restrict__ Wv, const float* __restrict__ Wo,
    unsigned short* __restrict__ WqT, unsigned short* __restrict__ WkT,
    unsigned short* __restrict__ WvT, unsigned short* __restrict__ WoT)
{
    int tid = blockIdx.x * 256 + threadIdx.x;   // 0..32767
    int n = tid >> 9, k = tid & 511;            // (n<64, k<512)
    WqT[tid] = f2bf(Wq[k * 64 + n]);
    WkT[tid] = f2bf(Wk[k * 64 + n]);
    WvT[tid] = f2bf(Wv[k * 64 + n]);
    int n2 = tid >> 6, k2 = tid & 63;           // (n2<512, k2<64)
    WoT[tid] = f2bf(Wo[k2 * 512 + n2]);
}

// ---------------- K1: fused QKV projection (byte-identical to R2's PROVEN
// kernel): one wave computes Q,K,V for 16 rows, x read ONCE (32 MB not 96 MB).
__global__ __launch_bounds__(64) void qkv_kernel(
    const float* __restrict__ x,
    const unsigned short* __restrict__ WqT, const unsigned short* __restrict__ WkT,
    const unsigned short* __restrict__ WvT,
    const float* __restrict__ bq, const float* __restrict__ bk, const float* __restrict__ bv,
    unsigned short* __restrict__ Qb, unsigned short* __restrict__ Kb,
    unsigned short* __restrict__ Vt)
{
    const int row0 = blockIdx.x * 16;
    const int lane = threadIdx.x, cl = lane & 15, quad = lane >> 4;
    floatx4 aQ[4], aK[4], aV[4];
    #pragma unroll
    for (int t = 0; t < 4; t++) { aQ[t] = (floatx4){0,0,0,0}; aK[t] = (floatx4){0,0,0,0}; aV[t] = (floatx4){0,0,0,0}; }
    const float* xrow = x + (size_t)(row0 + cl) * 512;
    #pragma unroll 2
    for (int kc = 0; kc < 16; kc++) {
        const int k0 = kc * 32 + quad * 8;
        float4 xa = *(const float4*)(xrow + k0);
        float4 xb = *(const float4*)(xrow + k0 + 4);
        bf16x8 af = cvt_bf16x8(xa, xb);
        #pragma unroll
        for (int t = 0; t < 4; t++) {
            const int widx = (t * 16 + cl) * 512 + k0;
            bf16x8 bQ = *(const bf16x8*)(const void*)(WqT + widx);
            bf16x8 bK = *(const bf16x8*)(const void*)(WkT + widx);
            bf16x8 bV = *(const bf16x8*)(const void*)(WvT + widx);
            aQ[t] = __builtin_amdgcn_mfma_f32_16x16x32_bf16(af, bQ, aQ[t], 0, 0, 0);
            aK[t] = __builtin_amdgcn_mfma_f32_16x16x32_bf16(af, bK, aK[t], 0, 0, 0);
            aV[t] = __builtin_amdgcn_mfma_f32_16x16x32_bf16(af, bV, aV[t], 0, 0, 0);
        }
    }
    const int b = row0 >> 12, s_base = row0 & 4095;
    #pragma unroll
    for (int t = 0; t < 4; t++) {
        const int d = t * 16 + cl;
        const float bqd = bq[d], bkd = bk[d], bvd = bv[d];
        #pragma unroll
        for (int r = 0; r < 4; r++) {
            const int rr = quad * 4 + r;
            Qb[(size_t)(row0 + rr) * 64 + d] = f2bf(aQ[t][r] + bqd);
            Kb[(size_t)(row0 + rr) * 64 + d] = f2bf(aK[t][r] + bkd);
            Vt[((size_t)b * 64 + d) * S_LEN + s_base + rr] = f2bf(aV[t][r] + bvd);
        }
    }
}

// ---------------- K2: causal flash attention, register-resident P.
// Swapped-operand QK (S^T in C-layout == PV A-layout after half-K packing),
// constant-max softmax (scores are /sqrt(4096): |z|<~1.2, exp2 cannot
// overflow), no in-loop LDS / cross-lane / rescale. Static LPT grid.
__global__ __launch_bounds__(256, 2) void attn_kernel(
    const unsigned short* __restrict__ Qb, const unsigned short* __restrict__ Kb,
    const unsigned short* __restrict__ Vt, unsigned short* __restrict__ Ob)
{
    __shared__ float Op[4][16][66];
    __shared__ float Ml[4][16];
    const int bid = blockIdx.x;              // 0..1023
    const int qt = 255 - (bid >> 2);         // longest-first (LPT)
    const int b = bid & 3;
    const int q0 = qt * 16;
    const int nkt = (qt >> 2) + 1;           // 64-key tiles in causal range
    const int tid = threadIdx.x;
    const int w = tid >> 6, lane = tid & 63, cl = lane & 15, quad = lane >> 4;

    const size_t qrow = (size_t)b * S_LEN + q0 + cl;
    const bf16x8 aq0 = *(const bf16x8*)(const void*)(Qb + qrow * 64 + quad * 8);
    const bf16x8 aq1 = *(const bf16x8*)(const void*)(Qb + qrow * 64 + 32 + quad * 8);
    const unsigned short* kbb = Kb + (size_t)b * S_LEN * 64;
    const unsigned short* vbb = Vt + (size_t)b * 64 * S_LEN;

    float lsum = 0.f;
    floatx4 Oacc[4];
    #pragma unroll
    for (int u = 0; u < 4; u++) Oacc[u] = (floatx4){0.f, 0.f, 0.f, 0.f};
    const float C2 = 0.022542110013890054f;  // log2(e)/sqrt(4096)

    for (int jt = w; jt < nkt; jt += 4) {
        const int j0 = jt * 64;
        // V half-frags: V[key=quad*4+j][d=u*16+cl], 8B each (PV B low half)
        uint2 vraw[4][4];
        #pragma unroll
        for (int t = 0; t < 4; t++)
            #pragma unroll
            for (int u = 0; u < 4; u++)
                vraw[t][u] = *(const uint2*)(const void*)
                    (vbb + (size_t)(u * 16 + cl) * S_LEN + j0 + t * 16 + quad * 4);
        // swapped QK -> S^T: lane(cl,quad) reg r = S[key=j0+t*16+quad*4+r][query=q0+cl]
        float p[4][4];
        #pragma unroll
        for (int t = 0; t < 4; t++) {
            const unsigned short* kp = kbb + (size_t)(j0 + t * 16 + cl) * 64 + quad * 8;
            bf16x8 k0f = *(const bf16x8*)(const void*)kp;
            bf16x8 k1f = *(const bf16x8*)(const void*)(kp + 32);
            floatx4 acc = (floatx4){0.f, 0.f, 0.f, 0.f};
            acc = __builtin_amdgcn_mfma_f32_16x16x32_bf16(k0f, aq0, acc, 0, 0, 0);
            acc = __builtin_amdgcn_mfma_f32_16x16x32_bf16(k1f, aq1, acc, 0, 0, 0);
            #pragma unroll
            for (int r = 0; r < 4; r++) p[t][r] = fast_exp2(acc[r] * C2);
        }
        if (jt == nkt - 1) {  // diagonal tile: zero masked keys (key > query)
            #pragma unroll
            for (int t = 0; t < 4; t++)
                #pragma unroll
                for (int r = 0; r < 4; r++)
                    if (j0 + t * 16 + quad * 4 + r > q0 + cl) p[t][r] = 0.f;
        }
        #pragma unroll
        for (int t = 0; t < 4; t++)
            lsum += (p[t][0] + p[t][1]) + (p[t][2] + p[t][3]);
        // PV: P packed into A low half (slots quad*8+0..3), zeros elsewhere
        #pragma unroll
        for (int t = 0; t < 4; t++) {
            frag8 ab;
            ab.u[0] = pack2bf(p[t][0], p[t][1]);
            ab.u[1] = pack2bf(p[t][2], p[t][3]);
            ab.u[2] = 0u; ab.u[3] = 0u;
            #pragma unroll
            for (int u = 0; u < 4; u++) {
                frag8 bb;
                bb.u[0] = vraw[t][u].x;
                bb.u[1] = vraw[t][u].y;
                bb.u[2] = 0u; bb.u[3] = 0u;
                Oacc[u] = __builtin_amdgcn_mfma_f32_16x16x32_bf16(ab.v, bb.v, Oacc[u], 0, 0, 0);
            }
        }
    }
    // l: per-lane partial covers keys (quad,r) for query=cl; reduce over quads
    lsum += __shfl_xor(lsum, 16, 64);
    lsum += __shfl_xor(lsum, 32, 64);
    // publish partials (Oacc in standard C-layout: row=query=quad*4+r, col=d=u*16+cl)
    #pragma unroll
    for (int u = 0; u < 4; u++)
        #pragma unroll
        for (int r = 0; r < 4; r++)
            Op[w][quad * 4 + r][u * 16 + cl] = Oacc[u][r];
    if (lane < 16) Ml[w][lane] = lsum;   // quad==0 lanes: query index == lane
    __syncthreads();
    // merge 4 wave-partials: plain sums (constant max), one divide
    {
        const int row = tid >> 4, d0 = (tid & 15) * 4;
        float L = (Ml[0][row] + Ml[1][row]) + (Ml[2][row] + Ml[3][row]);
        float invL = 1.0f / L;
        unsigned short ov[4];
        #pragma unroll
        for (int i = 0; i < 4; i++) {
            float o = (Op[0][row][d0 + i] + Op[1][row][d0 + i])
                    + (Op[2][row][d0 + i] + Op[3][row][d0 + i]);
            ov[i] = f2bf(o * invL);
        }
        *(uint2*)(void*)(Ob + ((size_t)b * S_LEN + q0 + row) * 64 + d0) = *(const uint2*)ov;
    }
}

// ---------------- K3: out = O @ Wo + bo via MFMA (unchanged, proven)
__global__ __launch_bounds__(256) void oproj_kernel(
    const unsigned short* __restrict__ Ob, const unsigned short* __restrict__ WoT,
    const float* __restrict__ bo, float* __restrict__ out)
{
    const int row0 = blockIdx.x * 16;
    const int tid = threadIdx.x;
    const int w = tid >> 6, lane = tid & 63, cl = lane & 15, quad = lane >> 4;
    const unsigned short* op = Ob + (size_t)(row0 + cl) * 64 + quad * 8;
    const bf16x8 a0 = *(const bf16x8*)(const void*)op;
    const bf16x8 a1 = *(const bf16x8*)(const void*)(op + 32);
    #pragma unroll 2
    for (int i = 0; i < 8; i++) {
        const int n = w * 128 + i * 16 + cl;
        const unsigned short* wp = WoT + (size_t)n * 64 + quad * 8;
        bf16x8 b0 = *(const bf16x8*)(const void*)wp;
        bf16x8 b1 = *(const bf16x8*)(const void*)(wp + 32);
        floatx4 acc = (floatx4){0.f, 0.f, 0.f, 0.f};
        acc = __builtin_amdgcn_mfma_f32_16x16x32_bf16(a0, b0, acc, 0, 0, 0);
        acc = __builtin_amdgcn_mfma_f32_16x16x32_bf16(a1, b1, acc, 0, 0, 0);
        const float bod = bo[n];
        #pragma unroll
        for (int r = 0; r < 4; r++)
            out[(size_t)(row0 + quad * 4 + r) * 512 + n] = acc[r] + bod;
    }
}

extern "C" void kernel_launch(void* const* d_in, const int* in_sizes, int n_in,
                              void* d_out, int out_size, void* d_ws, size_t ws_size,
                              hipStream_t stream) {
    const float* x  = (const float*)d_in[0];
    const float* Wq = (const float*)d_in[1];
    const float* bq = (const float*)d_in[2];
    const float* Wk = (const float*)d_in[3];
    const float* bk = (const float*)d_in[4];
    const float* Wv = (const float*)d_in[5];
    const float* bv = (const float*)d_in[6];
    const float* Wo = (const float*)d_in[7];
    const float* bo = (const float*)d_in[8];
    float* out = (float*)d_out;

    unsigned short* Qb  = (unsigned short*)d_ws;               // 2 MB
    unsigned short* Kb  = Qb + (size_t)NROWS * 64;             // 2 MB
    unsigned short* Vt  = Kb + (size_t)NROWS * 64;             // 2 MB (transposed [b][64][s])
    unsigned short* Ob  = Vt + (size_t)NROWS * 64;             // 2 MB (bf16 O, row-major)
    unsigned short* WqT = Ob + (size_t)NROWS * 64;             // 64 KB each
    unsigned short* WkT = WqT + 512 * 64;
    unsigned short* WvT = WkT + 512 * 64;
    unsigned short* WoT = WvT + 512 * 64;

    convw_kernel<<<128, 256, 0, stream>>>(Wq, Wk, Wv, Wo, WqT, WkT, WvT, WoT);
    qkv_kernel<<<NROWS / 16, 64, 0, stream>>>(x, WqT, WkT, WvT, bq, bk, bv, Qb, Kb, Vt);
    attn_kernel<<<1024, 256, 0, stream>>>(Qb, Kb, Vt, Ob);
    oproj_kernel<<<NROWS / 16, 256, 0, stream>>>(Ob, WoT, bo, out);
}